// Round 2
// baseline (617.466 us; speedup 1.0000x reference)
//
#include <hip/hip_runtime.h>

// ---- types ----
typedef __attribute__((ext_vector_type(4))) float f32x4;
typedef __attribute__((ext_vector_type(8))) __bf16 bf16x8;
typedef __attribute__((address_space(1))) unsigned int gu32;
typedef __attribute__((address_space(3))) unsigned int lu32;

// Problem constants: x (N=32, C=128, T=512, F=32) fp32
#define PN 32
#define PC 128
#define PT 512
#define PF 32

__device__ inline unsigned short f2bf(float x) {
  // round-to-nearest-even f32 -> bf16 bits
  unsigned int u = __float_as_uint(x);
  return (unsigned short)((u + 0x7FFFu + ((u >> 16) & 1u)) >> 16);
}

// ---------------------------------------------------------------------------
// Pass 1: transpose+convert  x[n][c][t][f] (f32) -> xt[(n*32+f)][c][t] (bf16)
// One block per (n,c) slab (512x32 f32 = 64 KB, contiguous).
// ---------------------------------------------------------------------------
__global__ __launch_bounds__(256) void pack_kernel(const float* __restrict__ x,
                                                   unsigned short* __restrict__ xt) {
  const int nc = blockIdx.x;            // n*128 + c
  const int n = nc >> 7, c = nc & 127;
  const float4* src4 = (const float4*)(x + (size_t)nc * (PT * PF));
  __shared__ unsigned short lds[32][520];   // [f][t] bf16 bits, padded rows
  const int tid = threadIdx.x;

  // read 512*32 floats as 4096 float4 (each float4 = 4 consecutive f, one t)
  #pragma unroll
  for (int i = 0; i < 16; ++i) {
    int idx = i * 256 + tid;            // 0..4095
    float4 v = src4[idx];
    int flat = idx << 2;                // t*32 + f
    int t = flat >> 5, f0 = flat & 31;
    lds[f0 + 0][t] = f2bf(v.x);
    lds[f0 + 1][t] = f2bf(v.y);
    lds[f0 + 2][t] = f2bf(v.z);
    lds[f0 + 3][t] = f2bf(v.w);
  }
  __syncthreads();

  // write 32 rows of 512 bf16 (1 KB each), coalesced ushort4
  #pragma unroll
  for (int i = 0; i < 16; ++i) {
    int idx = i * 256 + tid;            // ushort4 index, 0..4095
    int f = idx >> 7;                   // 128 ushort4 per f-row
    int t4 = (idx & 127) << 2;
    ushort4 v;
    v.x = lds[f][t4 + 0];
    v.y = lds[f][t4 + 1];
    v.z = lds[f][t4 + 2];
    v.w = lds[f][t4 + 3];
    ushort4* dst = (ushort4*)(xt + (((size_t)(n * PF + f) * PC + c) * PT));
    dst[idx & 127] = v;
  }
}

// ---------------------------------------------------------------------------
// Pass 2: per batch b = n*32+f, Gram = A·A^T with A = xt[b] (128x512 bf16),
// then kern = exp(-max(sq_i+sq_j-2g, 0)/(2*sigma^2)) -> out[n][i][j][f].
// One block (4 waves) computes the full 128x128 tile; BK=64 K-steps staged
// via global_load_lds width-16. sq taken from Gram diagonal => exact 0 diag.
// ---------------------------------------------------------------------------
__global__ __launch_bounds__(256) void gram_kernel(const unsigned short* __restrict__ xt,
                                                   const float* __restrict__ sigma,
                                                   float* __restrict__ out) {
  const int b = blockIdx.x;             // 0..1023
  const int n = b >> 5, f = b & 31;
  const unsigned short* A = xt + (size_t)b * PC * PT;

  __shared__ __align__(16) unsigned short lds[PC * 64];  // 16 KB: 128 rows x 64 bf16
  __shared__ float sq[PC];

  const int tid = threadIdx.x;
  const int wv = tid >> 6, ln = tid & 63;
  const int r0 = (wv >> 1) * 64, c0 = (wv & 1) * 64;   // wave's 64x64 quadrant
  const int lr = ln & 15, lq = ln >> 4;

  f32x4 acc[4][4];
  #pragma unroll
  for (int m = 0; m < 4; ++m)
    #pragma unroll
    for (int nn = 0; nn < 4; ++nn)
      acc[m][nn] = (f32x4){0.f, 0.f, 0.f, 0.f};

  for (int ks = 0; ks < 8; ++ks) {
    const int t0 = ks * 64;
    // stage A[0:128][t0:t0+64] -> lds (linear row-major [128][64])
    #pragma unroll
    for (int i = 0; i < 4; ++i) {
      int slot = i * 4 + wv;                       // 0..15, 8 rows per slot
      int crow = slot * 8 + (ln >> 3);
      const unsigned short* g = A + (size_t)crow * PT + t0 + (ln & 7) * 8;
      __builtin_amdgcn_global_load_lds((gu32*)g, (lu32*)(&lds[slot * 512]), 16, 0, 0);
    }
    __syncthreads();   // drains vmcnt before barrier (compiler-inserted)

    #pragma unroll
    for (int kk = 0; kk < 64; kk += 32) {
      bf16x8 av[4], bv[4];
      #pragma unroll
      for (int m = 0; m < 4; ++m)
        av[m] = *(const bf16x8*)(&lds[(r0 + m * 16 + lr) * 64 + kk + lq * 8]);
      #pragma unroll
      for (int m = 0; m < 4; ++m)
        bv[m] = *(const bf16x8*)(&lds[(c0 + m * 16 + lr) * 64 + kk + lq * 8]);
      #pragma unroll
      for (int m = 0; m < 4; ++m)
        #pragma unroll
        for (int nn = 0; nn < 4; ++nn)
          acc[m][nn] = __builtin_amdgcn_mfma_f32_16x16x32_bf16(av[m], bv[nn], acc[m][nn], 0, 0, 0);
    }
    __syncthreads();
  }

  // extract Gram diagonal -> sq[] (only frags with global row==col contribute)
  #pragma unroll
  for (int m = 0; m < 4; ++m) {
    int rowb = r0 + m * 16 + lq * 4;
    int col  = c0 + m * 16 + lr;
    #pragma unroll
    for (int j = 0; j < 4; ++j)
      if (rowb + j == col) sq[col] = acc[m][m][j];
  }
  __syncthreads();

  const float sg = sigma[0];
  const float inv = 0.5f / (sg * sg);
  float* ob = out + (size_t)n * PC * PC * PF + f;
  #pragma unroll
  for (int m = 0; m < 4; ++m) {
    #pragma unroll
    for (int nn = 0; nn < 4; ++nn) {
      int col = c0 + nn * 16 + lr;
      #pragma unroll
      for (int j = 0; j < 4; ++j) {
        int row = r0 + m * 16 + lq * 4 + j;
        float g = acc[m][nn][j];
        float d2 = sq[row] + sq[col] - 2.0f * g;
        d2 = fmaxf(d2, 0.0f);
        ob[((size_t)row * PC + col) * PF] = __expf(-d2 * inv);
      }
    }
  }
}

extern "C" void kernel_launch(void* const* d_in, const int* in_sizes, int n_in,
                              void* d_out, int out_size, void* d_ws, size_t ws_size,
                              hipStream_t stream) {
  const float* x = (const float*)d_in[0];
  const float* sigma = (const float*)d_in[1];
  float* out = (float*)d_out;
  unsigned short* xt = (unsigned short*)d_ws;   // needs 1024*128*512*2 = 128 MiB

  hipLaunchKernelGGL(pack_kernel, dim3(PN * PC), dim3(256), 0, stream, x, xt);
  hipLaunchKernelGGL(gram_kernel, dim3(PN * PF), dim3(256), 0, stream, xt, sigma, out);
}

// Round 3
// 444.897 us; speedup vs baseline: 1.3879x; 1.3879x over previous
//
#include <hip/hip_runtime.h>

// ---- types ----
typedef __attribute__((ext_vector_type(4))) float f32x4;
typedef __attribute__((ext_vector_type(8))) __bf16 bf16x8;
typedef __attribute__((address_space(1))) unsigned int gu32;
typedef __attribute__((address_space(3))) unsigned int lu32;

// Problem constants: x (N=32, C=128, T=512, F=32) fp32
#define PN 32
#define PC 128
#define PT 512
#define PF 32

__device__ inline unsigned short f2bf(float x) {
  // round-to-nearest-even f32 -> bf16 bits
  unsigned int u = __float_as_uint(x);
  return (unsigned short)((u + 0x7FFFu + ((u >> 16) & 1u)) >> 16);
}

// ---------------------------------------------------------------------------
// Pass 1: transpose+convert  x[n][c][t][f] (f32) -> xt[(n*32+f)][c][t] (bf16)
// One block per (n,c) slab (512x32 f32 = 64 KB, contiguous).
// Row pitch 522 ushorts (261 dwords, odd) -> scatter writes spread across banks.
// ---------------------------------------------------------------------------
__global__ __launch_bounds__(256) void pack_kernel(const float* __restrict__ x,
                                                   unsigned short* __restrict__ xt) {
  const int nc = blockIdx.x;            // n*128 + c
  const int n = nc >> 7, c = nc & 127;
  const float4* src4 = (const float4*)(x + (size_t)nc * (PT * PF));
  __shared__ unsigned short lds[32][522];   // [f][t] bf16 bits
  const int tid = threadIdx.x;

  // read 512*32 floats as 4096 float4 (each float4 = 4 consecutive f, one t)
  #pragma unroll
  for (int i = 0; i < 16; ++i) {
    int idx = i * 256 + tid;            // 0..4095
    float4 v = src4[idx];
    int flat = idx << 2;                // t*32 + f
    int t = flat >> 5, f0 = flat & 31;
    lds[f0 + 0][t] = f2bf(v.x);
    lds[f0 + 1][t] = f2bf(v.y);
    lds[f0 + 2][t] = f2bf(v.z);
    lds[f0 + 3][t] = f2bf(v.w);
  }
  __syncthreads();

  // write 32 rows of 512 bf16 (1 KB each), coalesced ushort4
  #pragma unroll
  for (int i = 0; i < 16; ++i) {
    int idx = i * 256 + tid;            // ushort4 index, 0..4095
    int f = idx >> 7;                   // 128 ushort4 per f-row
    int t4 = (idx & 127) << 2;
    ushort4 v;
    v.x = lds[f][t4 + 0];
    v.y = lds[f][t4 + 1];
    v.z = lds[f][t4 + 2];
    v.w = lds[f][t4 + 3];
    ushort4* dst = (ushort4*)(xt + (((size_t)(n * PF + f) * PC + c) * PT));
    dst[idx & 127] = v;
  }
}

// ---------------------------------------------------------------------------
// Pass 2: per batch b = n*32+f, Gram = A·A^T with A = xt[b] (128x512 bf16),
// kern = exp(-max(sq_i+sq_j-2g,0)/(2 sigma^2)).
// LDS tile [128][64] bf16 with 16B-block XOR swizzle (blk ^= row&7):
//   global_load_lds dest stays linear; the SOURCE address is inverse-swizzled
//   (rule: both-sides-or-neither), reads apply the same XOR -> 2-way max.
// COAL=true: write (n,f,i,j)-contiguous tmp (64B-coalesced dword stores).
// COAL=false: legacy direct strided write to out (fallback if ws too small).
// ---------------------------------------------------------------------------
template <bool COAL>
__global__ __launch_bounds__(256) void gram_kernel(const unsigned short* __restrict__ xt,
                                                   const float* __restrict__ sigma,
                                                   float* __restrict__ dst) {
  const int b = blockIdx.x;             // 0..1023
  const int n = b >> 5, f = b & 31;
  const unsigned short* A = xt + (size_t)b * PC * PT;

  __shared__ __align__(16) unsigned short lds[PC * 64];  // 16 KB
  __shared__ float sq[PC];

  const int tid = threadIdx.x;
  const int wv = tid >> 6, ln = tid & 63;
  const int r0 = (wv >> 1) * 64, c0 = (wv & 1) * 64;   // wave's 64x64 quadrant
  const int lr = ln & 15, lq = ln >> 4;

  f32x4 acc[4][4];
  #pragma unroll
  for (int m = 0; m < 4; ++m)
    #pragma unroll
    for (int nn = 0; nn < 4; ++nn)
      acc[m][nn] = (f32x4){0.f, 0.f, 0.f, 0.f};

  const int srow = ln >> 3;                  // row-within-8 this lane stages
  const int sblk = (ln & 7) ^ srow;          // inverse-swizzled global 16B block

  for (int ks = 0; ks < 8; ++ks) {
    const int t0 = ks * 64;
    #pragma unroll
    for (int i = 0; i < 4; ++i) {
      int slot = i * 4 + wv;                 // 0..15, 8 rows per slot
      int crow = slot * 8 + srow;
      const unsigned short* g = A + (size_t)crow * PT + t0 + sblk * 8;
      __builtin_amdgcn_global_load_lds((gu32*)g, (lu32*)(&lds[slot * 512]), 16, 0, 0);
    }
    __syncthreads();

    #pragma unroll
    for (int kk = 0; kk < 64; kk += 32) {
      bf16x8 av[4], bv[4];
      #pragma unroll
      for (int m = 0; m < 4; ++m) {
        int row = r0 + m * 16 + lr;
        av[m] = *(const bf16x8*)((const char*)lds + row * 128 +
                                 ((((kk >> 3) + lq) ^ (row & 7)) << 4));
      }
      #pragma unroll
      for (int m = 0; m < 4; ++m) {
        int row = c0 + m * 16 + lr;
        bv[m] = *(const bf16x8*)((const char*)lds + row * 128 +
                                 ((((kk >> 3) + lq) ^ (row & 7)) << 4));
      }
      #pragma unroll
      for (int m = 0; m < 4; ++m)
        #pragma unroll
        for (int nn = 0; nn < 4; ++nn)
          acc[m][nn] = __builtin_amdgcn_mfma_f32_16x16x32_bf16(av[m], bv[nn], acc[m][nn], 0, 0, 0);
    }
    __syncthreads();
  }

  // Gram diagonal -> sq[] (frags with global row==col; waves 0/3 cover all 128)
  #pragma unroll
  for (int m = 0; m < 4; ++m) {
    int rowb = r0 + m * 16 + lq * 4;
    int col  = c0 + m * 16 + lr;
    #pragma unroll
    for (int j = 0; j < 4; ++j)
      if (rowb + j == col) sq[col] = acc[m][m][j];
  }
  __syncthreads();

  const float sg = sigma[0];
  const float inv = 0.5f / (sg * sg);
  #pragma unroll
  for (int m = 0; m < 4; ++m) {
    #pragma unroll
    for (int nn = 0; nn < 4; ++nn) {
      int col = c0 + nn * 16 + lr;
      #pragma unroll
      for (int j = 0; j < 4; ++j) {
        int row = r0 + m * 16 + lq * 4 + j;
        float g = acc[m][nn][j];
        float d2 = fmaxf(sq[row] + sq[col] - 2.0f * g, 0.0f);
        float v = __expf(-d2 * inv);
        if (COAL) {
          // tmp[(n*32+f)][row][col] — 16 consecutive lanes = 64B contiguous
          dst[(size_t)b * (PC * PC) + row * PC + col] = v;
        } else {
          dst[(size_t)n * (PC * PC * PF) + ((size_t)row * PC + col) * PF + f] = v;
        }
      }
    }
  }
}

// ---------------------------------------------------------------------------
// Pass 3: tmp (n,f,i,j) -> out (n,i,j,f). Block per (n,i): reads 32 f-rows of
// 128 floats (coalesced, mostly L3-hot), writes one 16 KB contiguous slab.
// LDS [32][129] floats: pitch 129 dwords (odd) -> both phases <=2-way banks.
// ---------------------------------------------------------------------------
__global__ __launch_bounds__(256) void unpermute_kernel(const float* __restrict__ tmp,
                                                        float* __restrict__ out) {
  const int blk = blockIdx.x;           // n*128 + i
  const int n = blk >> 7, i = blk & 127;
  __shared__ float lds[PF][PC + 1];     // [f][j]
  const int tid = threadIdx.x;

  const float* src = tmp + (size_t)n * PF * PC * PC + (size_t)i * PC;
  #pragma unroll
  for (int it = 0; it < 16; ++it) {
    int idx = it * 256 + tid;           // 0..4095
    int fr = idx >> 7, j = idx & 127;
    lds[fr][j] = src[(size_t)fr * (PC * PC) + j];
  }
  __syncthreads();

  float4* dst4 = (float4*)(out + ((size_t)(n * PC) + i) * (PC * PF));
  #pragma unroll
  for (int it = 0; it < 4; ++it) {
    int idx4 = it * 256 + tid;          // 0..1023 float4s of the 16 KB slab
    int j = idx4 >> 3, f0 = (idx4 & 7) << 2;
    float4 v;
    v.x = lds[f0 + 0][j];
    v.y = lds[f0 + 1][j];
    v.z = lds[f0 + 2][j];
    v.w = lds[f0 + 3][j];
    dst4[idx4] = v;
  }
}

extern "C" void kernel_launch(void* const* d_in, const int* in_sizes, int n_in,
                              void* d_out, int out_size, void* d_ws, size_t ws_size,
                              hipStream_t stream) {
  const float* x = (const float*)d_in[0];
  const float* sigma = (const float*)d_in[1];
  float* out = (float*)d_out;

  unsigned short* xt = (unsigned short*)d_ws;             // 128 MiB
  const size_t xt_bytes = (size_t)PN * PF * PC * PT * 2;
  const size_t tmp_bytes = (size_t)PN * PF * PC * PC * 4; // 64 MiB
  const bool coal = ws_size >= xt_bytes + tmp_bytes;

  hipLaunchKernelGGL(pack_kernel, dim3(PN * PC), dim3(256), 0, stream, x, xt);
  if (coal) {
    float* tmp = (float*)((char*)d_ws + xt_bytes);
    hipLaunchKernelGGL((gram_kernel<true>), dim3(PN * PF), dim3(256), 0, stream, xt, sigma, tmp);
    hipLaunchKernelGGL(unpermute_kernel, dim3(PN * PC), dim3(256), 0, stream, tmp, out);
  } else {
    hipLaunchKernelGGL((gram_kernel<false>), dim3(PN * PF), dim3(256), 0, stream, xt, sigma, out);
  }
}

// Round 4
// 433.355 us; speedup vs baseline: 1.4248x; 1.0266x over previous
//
#include <hip/hip_runtime.h>

// ---- types ----
typedef __attribute__((ext_vector_type(4))) float f32x4;
typedef __attribute__((ext_vector_type(8))) __bf16 bf16x8;
typedef __attribute__((address_space(1))) unsigned int gu32;
typedef __attribute__((address_space(3))) unsigned int lu32;

// Problem constants: x (N=32, C=128, T=512, F=32) fp32
#define PN 32
#define PC 128
#define PT 512
#define PF 32

__device__ inline unsigned short f2bf(float x) {
  unsigned int u = __float_as_uint(x);
  return (unsigned short)((u + 0x7FFFu + ((u >> 16) & 1u)) >> 16);
}
__device__ inline float bf2f(unsigned short b) {
  return __uint_as_float(((unsigned int)b) << 16);
}

// ---------------------------------------------------------------------------
// Pass 1 (UNCHANGED from round 3 — control variable):
// x[n][c][t][f] (f32) -> xt[(n*32+f)][c][t] (bf16). Block per (n,c) slab.
// ---------------------------------------------------------------------------
__global__ __launch_bounds__(256) void pack_kernel(const float* __restrict__ x,
                                                   unsigned short* __restrict__ xt) {
  const int nc = blockIdx.x;            // n*128 + c
  const int n = nc >> 7, c = nc & 127;
  const float4* src4 = (const float4*)(x + (size_t)nc * (PT * PF));
  __shared__ unsigned short lds[32][522];   // [f][t] bf16 bits
  const int tid = threadIdx.x;

  #pragma unroll
  for (int i = 0; i < 16; ++i) {
    int idx = i * 256 + tid;            // 0..4095
    float4 v = src4[idx];
    int flat = idx << 2;                // t*32 + f
    int t = flat >> 5, f0 = flat & 31;
    lds[f0 + 0][t] = f2bf(v.x);
    lds[f0 + 1][t] = f2bf(v.y);
    lds[f0 + 2][t] = f2bf(v.z);
    lds[f0 + 3][t] = f2bf(v.w);
  }
  __syncthreads();

  #pragma unroll
  for (int i = 0; i < 16; ++i) {
    int idx = i * 256 + tid;            // ushort4 index, 0..4095
    int f = idx >> 7;
    int t4 = (idx & 127) << 2;
    ushort4 v;
    v.x = lds[f][t4 + 0];
    v.y = lds[f][t4 + 1];
    v.z = lds[f][t4 + 2];
    v.w = lds[f][t4 + 3];
    ushort4* dst = (ushort4*)(xt + (((size_t)(n * PF + f) * PC + c) * PT));
    dst[idx & 127] = v;
  }
}

// ---------------------------------------------------------------------------
// Pass 2: b = n*32+f, Gram = A·A^T (A = xt[b], 128x512 bf16), then
// kern = exp(-max(sq_i+sq_j-2g,0)/(2 sigma^2)).
// NEW: 2-phase double-buffered K-pipeline (stage next tile before computing
// current; one barrier per K-step drains vmcnt+lgkmcnt). 16B-block XOR
// swizzle (blk ^= row&7): linear LDS dest + inverse-swizzled global source +
// swizzled reads. COAL: writes bf16 tmp (n,f,i,j); else legacy f32 direct.
// ---------------------------------------------------------------------------
template <bool COAL>
__global__ __launch_bounds__(256) void gram_kernel(const unsigned short* __restrict__ xt,
                                                   const float* __restrict__ sigma,
                                                   void* __restrict__ dstv) {
  const int b = blockIdx.x;             // 0..1023
  const int n = b >> 5, f = b & 31;
  const unsigned short* A = xt + (size_t)b * PC * PT;

  __shared__ __align__(16) unsigned short lds[2][PC * 64];  // 2 x 16 KB
  __shared__ float sq[PC];

  const int tid = threadIdx.x;
  const int wv = tid >> 6, ln = tid & 63;
  const int r0 = (wv >> 1) * 64, c0 = (wv & 1) * 64;   // wave's 64x64 quadrant
  const int lr = ln & 15, lq = ln >> 4;

  f32x4 acc[4][4];
  #pragma unroll
  for (int m = 0; m < 4; ++m)
    #pragma unroll
    for (int nn = 0; nn < 4; ++nn)
      acc[m][nn] = (f32x4){0.f, 0.f, 0.f, 0.f};

  const int srow = ln >> 3;                  // row-within-8 this lane stages
  const int sblk = (ln & 7) ^ srow;          // inverse-swizzled global 16B block

  // prologue: stage K-tile 0 into buf 0
  #pragma unroll
  for (int i = 0; i < 4; ++i) {
    int slot = i * 4 + wv;
    int crow = slot * 8 + srow;
    const unsigned short* g = A + (size_t)crow * PT + 0 + sblk * 8;
    __builtin_amdgcn_global_load_lds((gu32*)g, (lu32*)(&lds[0][slot * 512]), 16, 0, 0);
  }
  __syncthreads();

  for (int ks = 0; ks < 8; ++ks) {
    // issue next tile's loads into the other buffer (overlaps with compute)
    if (ks < 7) {
      const int t1 = (ks + 1) * 64;
      #pragma unroll
      for (int i = 0; i < 4; ++i) {
        int slot = i * 4 + wv;
        int crow = slot * 8 + srow;
        const unsigned short* g = A + (size_t)crow * PT + t1 + sblk * 8;
        __builtin_amdgcn_global_load_lds((gu32*)g, (lu32*)(&lds[(ks + 1) & 1][slot * 512]), 16, 0, 0);
      }
    }
    const unsigned short* L = lds[ks & 1];
    #pragma unroll
    for (int kk = 0; kk < 64; kk += 32) {
      bf16x8 av[4], bv[4];
      #pragma unroll
      for (int m = 0; m < 4; ++m) {
        int row = r0 + m * 16 + lr;
        av[m] = *(const bf16x8*)((const char*)L + row * 128 +
                                 ((((kk >> 3) + lq) ^ (row & 7)) << 4));
      }
      #pragma unroll
      for (int m = 0; m < 4; ++m) {
        int row = c0 + m * 16 + lr;
        bv[m] = *(const bf16x8*)((const char*)L + row * 128 +
                                 ((((kk >> 3) + lq) ^ (row & 7)) << 4));
      }
      #pragma unroll
      for (int m = 0; m < 4; ++m)
        #pragma unroll
        for (int nn = 0; nn < 4; ++nn)
          acc[m][nn] = __builtin_amdgcn_mfma_f32_16x16x32_bf16(av[m], bv[nn], acc[m][nn], 0, 0, 0);
    }
    __syncthreads();   // drains vmcnt (next tile ready) + lgkmcnt, then barrier
  }

  // Gram diagonal -> sq[] (waves 0/3 have r0==c0, covering all 128 entries)
  #pragma unroll
  for (int m = 0; m < 4; ++m) {
    int rowb = r0 + m * 16 + lq * 4;
    int col  = c0 + m * 16 + lr;
    #pragma unroll
    for (int j = 0; j < 4; ++j)
      if (rowb + j == col) sq[col] = acc[m][m][j];
  }
  __syncthreads();

  const float sg = sigma[0];
  const float inv = 0.5f / (sg * sg);
  #pragma unroll
  for (int m = 0; m < 4; ++m) {
    #pragma unroll
    for (int nn = 0; nn < 4; ++nn) {
      int col = c0 + nn * 16 + lr;
      #pragma unroll
      for (int j = 0; j < 4; ++j) {
        int row = r0 + m * 16 + lq * 4 + j;
        float g = acc[m][nn][j];
        float d2 = fmaxf(sq[row] + sq[col] - 2.0f * g, 0.0f);
        float v = __expf(-d2 * inv);
        if (COAL) {
          ((unsigned short*)dstv)[(size_t)b * (PC * PC) + row * PC + col] = f2bf(v);
        } else {
          ((float*)dstv)[(size_t)n * (PC * PC * PF) + ((size_t)row * PC + col) * PF + f] = v;
        }
      }
    }
  }
}

// ---------------------------------------------------------------------------
// Pass 3: tmp bf16 (n,f,i,j) -> out f32 (n,i,j,f). Block per (n,i).
// ---------------------------------------------------------------------------
__global__ __launch_bounds__(256) void unpermute_kernel(const unsigned short* __restrict__ tmp,
                                                        float* __restrict__ out) {
  const int blk = blockIdx.x;           // n*128 + i
  const int n = blk >> 7, i = blk & 127;
  __shared__ float lds[PF][PC + 1];     // [f][j]
  const int tid = threadIdx.x;

  const unsigned short* src = tmp + (size_t)n * PF * PC * PC + (size_t)i * PC;
  #pragma unroll
  for (int it = 0; it < 4; ++it) {
    int idx4 = it * 256 + tid;          // 0..1023 ushort4s
    int fr = idx4 >> 5, j4 = (idx4 & 31) << 2;
    ushort4 v = *(const ushort4*)(src + (size_t)fr * (PC * PC) + j4);
    lds[fr][j4 + 0] = bf2f(v.x);
    lds[fr][j4 + 1] = bf2f(v.y);
    lds[fr][j4 + 2] = bf2f(v.z);
    lds[fr][j4 + 3] = bf2f(v.w);
  }
  __syncthreads();

  float4* dst4 = (float4*)(out + ((size_t)(n * PC) + i) * (PC * PF));
  #pragma unroll
  for (int it = 0; it < 4; ++it) {
    int idx4 = it * 256 + tid;          // 0..1023 float4s
    int j = idx4 >> 3, f0 = (idx4 & 7) << 2;
    float4 v;
    v.x = lds[f0 + 0][j];
    v.y = lds[f0 + 1][j];
    v.z = lds[f0 + 2][j];
    v.w = lds[f0 + 3][j];
    dst4[idx4] = v;
  }
}

extern "C" void kernel_launch(void* const* d_in, const int* in_sizes, int n_in,
                              void* d_out, int out_size, void* d_ws, size_t ws_size,
                              hipStream_t stream) {
  const float* x = (const float*)d_in[0];
  const float* sigma = (const float*)d_in[1];
  float* out = (float*)d_out;

  unsigned short* xt = (unsigned short*)d_ws;              // 128 MiB
  const size_t xt_bytes = (size_t)PN * PF * PC * PT * 2;
  const size_t tmp_bytes = (size_t)PN * PF * PC * PC * 2;  // 32 MiB (bf16)
  const bool coal = ws_size >= xt_bytes + tmp_bytes;

  hipLaunchKernelGGL(pack_kernel, dim3(PN * PC), dim3(256), 0, stream, x, xt);
  if (coal) {
    unsigned short* tmp = (unsigned short*)((char*)d_ws + xt_bytes);
    hipLaunchKernelGGL((gram_kernel<true>), dim3(PN * PF), dim3(256), 0, stream, xt, sigma, (void*)tmp);
    hipLaunchKernelGGL(unpermute_kernel, dim3(PN * PC), dim3(256), 0, stream, tmp, out);
  } else {
    hipLaunchKernelGGL((gram_kernel<false>), dim3(PN * PF), dim3(256), 0, stream, xt, sigma, (void*)out);
  }
}